// Round 3
// baseline (431.192 us; speedup 1.0000x reference)
//
#include <hip/hip_runtime.h>

// AutoEncoderLoss: two-level segment-mean MSE over seg = b*128 + c.
// R3: half-wave-replicated LDS u64 histograms (8 replicas, collisions only
// within 32 lanes) + finalize fused into the last-finishing block
// (device atomic counter; coherent gseg readback via atomicAdd(p,0)).
// enc = (1 << 44) | round(d^2 * 2^20): count high bits, fixed-point sum low.
// batch_index sorted -> per-block chunk single-batch except boundary blocks.

#define BATCHES 32
#define CLUSTERS 128
#define NSEG (BATCHES * CLUSTERS)
#define BLOCK 256
#define REPS 8                   // one replica per 32-lane half-wave
#define EPB 4096                 // elements per block = 256 threads x 4 iters x 4
#define SHIFT 44
#define SCALE 1048576.0f         // 2^20
#define INV_SCALE (1.0f / 1048576.0f)
#define SUM_MASK ((1ULL << SHIFT) - 1)

typedef unsigned long long u64;

__device__ __forceinline__ u64 enc_elem(float d) {
    return (1ULL << SHIFT) + (u64)__float2uint_rn(d * d * SCALE);
}

__global__ __launch_bounds__(BLOCK) void fused_loss_kernel(
    const float* __restrict__ reco,
    const float* __restrict__ target,
    const int* __restrict__ clabel,
    const int* __restrict__ batch_index,
    u64* __restrict__ gseg,
    unsigned* __restrict__ counter,
    float* __restrict__ out,
    int n)
{
    __shared__ u64 hist[REPS][2 * CLUSTERS];
    __shared__ float bl[BATCHES];
    __shared__ float bp[BATCHES];
    __shared__ int last_flag;

    const int tid = threadIdx.x;
    const int rep = tid >> 5;    // half-wave replica index 0..7

    for (int s = tid; s < REPS * 2 * CLUSTERS; s += BLOCK)
        ((u64*)hist)[s] = 0ULL;
    __syncthreads();

    const long long base = (long long)blockIdx.x * EPB;
    if (base < (long long)n) {
        const long long lim = (base + EPB <= (long long)n) ? base + EPB : (long long)n;
        const int b0 = batch_index[base];
        const int bL = batch_index[lim - 1];
        u64* h = hist[rep];

        if (b0 == bL && base + EPB <= (long long)n) {
            // single-batch full chunk: no per-element batch load
            #pragma unroll
            for (int k = 0; k < EPB / (BLOCK * 4); ++k) {
                const long long idx = base + (long long)(k * BLOCK + tid) * 4;
                const float4 r = *(const float4*)(reco + idx);
                const float4 t = *(const float4*)(target + idx);
                const int4   c = *(const int4*)(clabel + idx);
                atomicAdd(&h[c.x], enc_elem(r.x - t.x));
                atomicAdd(&h[c.y], enc_elem(r.y - t.y));
                atomicAdd(&h[c.z], enc_elem(r.z - t.z));
                atomicAdd(&h[c.w], enc_elem(r.w - t.w));
            }
        } else {
            // boundary / tail path (rare)
            for (long long idx = base + tid; idx < lim; idx += BLOCK) {
                const float d = reco[idx] - target[idx];
                const int b = batch_index[idx];
                const int c = clabel[idx];
                const u64 enc = enc_elem(d);
                const int rel = b - b0;
                if (rel < 2) atomicAdd(&h[rel * CLUSTERS + c], enc);
                else         atomicAdd(&gseg[(long long)b * CLUSTERS + c], enc);
            }
        }
        __syncthreads();

        // combine replicas, sparse flush (zero entries skipped -> no OOB
        // for the unused upper half when b0 is the last batch)
        for (int s = tid; s < 2 * CLUSTERS; s += BLOCK) {
            u64 v = 0;
            #pragma unroll
            for (int r = 0; r < REPS; ++r) v += hist[r][s];
            if (v) atomicAdd(&gseg[(long long)b0 * CLUSTERS + s], v);
        }
    }

    // ---- completion count: last block to arrive does the finalize ----
    __threadfence();
    if (tid == 0) {
        const unsigned old = atomicAdd(counter, 1u);
        last_flag = (old == gridDim.x - 1) ? 1 : 0;
    }
    __syncthreads();
    if (!last_flag) return;

    // Final block: all prior flush atomics are globally visible (each block
    // fenced before incrementing). Read gseg via device-scope RMW to bypass
    // any stale local cache lines.
    const int b    = tid >> 3;   // 32 batches x 8 threads
    const int part = tid & 7;
    float sm = 0.0f, np = 0.0f;
    #pragma unroll
    for (int j = 0; j < 16; ++j) {
        const u64 v = atomicAdd(&gseg[b * CLUSTERS + part * 16 + j], 0ULL);
        if (v) {  // nonzero iff count > 0
            const float cnt = (float)(unsigned)(v >> SHIFT);
            sm += ((float)(v & SUM_MASK) * INV_SCALE) / cnt;
            np += 1.0f;
        }
    }
    #pragma unroll
    for (int off = 4; off; off >>= 1) {
        sm += __shfl_down(sm, off, 8);
        np += __shfl_down(np, off, 8);
    }
    if (part == 0) {
        bl[b] = (np > 0.0f) ? (sm / np) : 0.0f;
        bp[b] = (np > 0.0f) ? 1.0f : 0.0f;
    }
    __syncthreads();
    if (tid == 0) {
        float s = 0.0f, nb = 0.0f;
        #pragma unroll
        for (int i = 0; i < BATCHES; ++i) { s += bl[i]; nb += bp[i]; }
        out[0] = (nb > 0.0f) ? (s / nb) : 0.0f;
    }
}

extern "C" void kernel_launch(void* const* d_in, const int* in_sizes, int n_in,
                              void* d_out, int out_size, void* d_ws, size_t ws_size,
                              hipStream_t stream) {
    const float* reco        = (const float*)d_in[0];
    const float* target      = (const float*)d_in[1];
    const int*   clabel      = (const int*)d_in[2];
    const int*   batch_index = (const int*)d_in[3];
    const int n = in_sizes[0];

    u64* gseg         = (u64*)d_ws;
    unsigned* counter = (unsigned*)((char*)d_ws + NSEG * sizeof(u64));

    // ws re-poisoned to 0xAA before every call: zero gseg + counter.
    hipMemsetAsync(d_ws, 0, NSEG * sizeof(u64) + 16, stream);

    const int nblocks = (n + EPB - 1) / EPB;
    fused_loss_kernel<<<nblocks, BLOCK, 0, stream>>>(
        reco, target, clabel, batch_index, gseg, counter, (float*)d_out, n);
}

// Round 4
// 198.396 us; speedup vs baseline: 2.1734x; 2.1734x over previous
//
#include <hip/hip_runtime.h>

// AutoEncoderLoss: two-level segment-mean MSE over seg = b*128 + c.
// R4: revert R3's fence+counter fusion (per-block device fences drain XCD L2
// -> 330us pathology). Structure:
//   K1: per-block LDS u64 histograms (4 full-wave replicas, native ds_add_u64,
//       enc = (1<<44)|round(d^2 * 2^20)), flushed NON-atomically to a private
//       scratch row per block (+ block's first batch id b0).
//   K2: 32 blocks (one per batch) binary-search sorted b0[], sum contributing
//       rows (b0 == b lower half, b0 == b-1 upper half), per-cluster means,
//       masked per-batch mean.
//   K3: 1 block combines 32 batch losses with present-batch masking.

#define BATCHES 32
#define CLUSTERS 128
#define NSEG (BATCHES * CLUSTERS)
#define BLOCK 256
#define REPS 4                   // one replica per full 64-lane wave
#define EPB 4096                 // elements per block = 256 threads x 4 iters x 4
#define SHIFT 44
#define SCALE 1048576.0f         // 2^20
#define INV_SCALE (1.0f / 1048576.0f)
#define SUM_MASK ((1ULL << SHIFT) - 1)

typedef unsigned long long u64;

__device__ __forceinline__ u64 enc_elem(float d) {
    return (1ULL << SHIFT) + (u64)__float2uint_rn(d * d * SCALE);
}

__global__ __launch_bounds__(BLOCK) void seg_accum_kernel(
    const float* __restrict__ reco,
    const float* __restrict__ target,
    const int* __restrict__ clabel,
    const int* __restrict__ batch_index,
    u64* __restrict__ scratch,   // [gridDim.x * 2*CLUSTERS], private row per block
    int* __restrict__ b0_arr,    // [gridDim.x]
    u64* __restrict__ oseg,      // [NSEG] overflow for chunks spanning >2 batches (zeroed)
    int n)
{
    __shared__ u64 hist[REPS][2 * CLUSTERS];
    const int tid  = threadIdx.x;
    const int wave = tid >> 6;

    const long long base = (long long)blockIdx.x * EPB;
    if (base >= n) {  // exact grid for N=2^23 -> never taken; keep sorted order
        if (tid == 0) b0_arr[blockIdx.x] = 0x7fffffff;
        return;
    }

    for (int s = tid; s < REPS * 2 * CLUSTERS; s += BLOCK)
        ((u64*)hist)[s] = 0ULL;
    __syncthreads();

    const long long lim = (base + EPB <= (long long)n) ? base + EPB : (long long)n;
    const int b0 = batch_index[base];
    const int bL = batch_index[lim - 1];
    u64* h = hist[wave];

    if (b0 == bL && base + EPB <= (long long)n) {
        // single-batch full chunk: no per-element batch load
        #pragma unroll
        for (int k = 0; k < EPB / (BLOCK * 4); ++k) {
            const long long idx = base + (long long)(k * BLOCK + tid) * 4;
            const float4 r = *(const float4*)(reco + idx);
            const float4 t = *(const float4*)(target + idx);
            const int4   c = *(const int4*)(clabel + idx);
            atomicAdd(&h[c.x], enc_elem(r.x - t.x));
            atomicAdd(&h[c.y], enc_elem(r.y - t.y));
            atomicAdd(&h[c.z], enc_elem(r.z - t.z));
            atomicAdd(&h[c.w], enc_elem(r.w - t.w));
        }
    } else {
        // boundary / tail path (~31 of 2048 blocks)
        for (long long idx = base + tid; idx < lim; idx += BLOCK) {
            const float d = reco[idx] - target[idx];
            const int b = batch_index[idx];
            const int c = clabel[idx];
            const u64 enc = enc_elem(d);
            const int rel = b - b0;
            if (rel < 2) atomicAdd(&h[rel * CLUSTERS + c], enc);
            else         atomicAdd(&oseg[(long long)b * CLUSTERS + c], enc);  // ~never
        }
    }
    __syncthreads();

    // combine replicas; non-atomic flush of ALL 256 entries (zeros included:
    // K2 reads both halves unconditionally)
    u64* srow = scratch + (long long)blockIdx.x * (2 * CLUSTERS);
    for (int s = tid; s < 2 * CLUSTERS; s += BLOCK) {
        srow[s] = hist[0][s] + hist[1][s] + hist[2][s] + hist[3][s];
    }
    if (tid == 0) b0_arr[blockIdx.x] = b0;
}

__global__ __launch_bounds__(128) void batch_reduce_kernel(
    const u64* __restrict__ scratch,
    const int* __restrict__ b0_arr,
    const u64* __restrict__ oseg,
    float* __restrict__ bl,      // [BATCHES]
    float* __restrict__ bp,      // [BATCHES]
    int nblocks)
{
    const int b = blockIdx.x;    // one block per batch
    const int c = threadIdx.x;   // 0..127 = cluster

    // blocks with b0 in {b-1, b} can contribute to batch b (sorted b0_arr)
    int lo = 0, hi = nblocks;
    while (lo < hi) { const int m = (lo + hi) >> 1; if (b0_arr[m] < b - 1) lo = m + 1; else hi = m; }
    int lo2 = lo, hi2 = nblocks;
    while (lo2 < hi2) { const int m = (lo2 + hi2) >> 1; if (b0_arr[m] < b + 1) lo2 = m + 1; else hi2 = m; }

    u64 acc = oseg[b * CLUSTERS + c];
    for (int j = lo; j < lo2; ++j) {
        const int bj = b0_arr[j];                      // wave-uniform
        const int off = (bj == b) ? c : (CLUSTERS + c);
        acc += scratch[(long long)j * (2 * CLUSTERS) + off];
    }

    float sm = 0.0f, np = 0.0f;
    if (acc) {  // nonzero iff count > 0
        const float cnt = (float)(unsigned)(acc >> SHIFT);
        sm = ((float)(acc & SUM_MASK) * INV_SCALE) / cnt;
        np = 1.0f;
    }
    // reduce 128 threads = 2 waves
    #pragma unroll
    for (int off = 32; off; off >>= 1) {
        sm += __shfl_down(sm, off);
        np += __shfl_down(np, off);
    }
    __shared__ float ssm[2], snp[2];
    if ((threadIdx.x & 63) == 0) { ssm[threadIdx.x >> 6] = sm; snp[threadIdx.x >> 6] = np; }
    __syncthreads();
    if (threadIdx.x == 0) {
        const float S = ssm[0] + ssm[1];
        const float P = snp[0] + snp[1];
        bl[b] = (P > 0.0f) ? (S / P) : 0.0f;
        bp[b] = (P > 0.0f) ? 1.0f : 0.0f;
    }
}

__global__ __launch_bounds__(64) void final_kernel(
    const float* __restrict__ bl,
    const float* __restrict__ bp,
    float* __restrict__ out)
{
    const int t = threadIdx.x;
    float s = 0.0f, nb = 0.0f;
    if (t < BATCHES) { s = bl[t]; nb = bp[t]; }
    #pragma unroll
    for (int off = 16; off; off >>= 1) {
        s  += __shfl_down(s, off, 32);
        nb += __shfl_down(nb, off, 32);
    }
    if (t == 0) out[0] = (nb > 0.0f) ? (s / nb) : 0.0f;
}

extern "C" void kernel_launch(void* const* d_in, const int* in_sizes, int n_in,
                              void* d_out, int out_size, void* d_ws, size_t ws_size,
                              hipStream_t stream) {
    const float* reco        = (const float*)d_in[0];
    const float* target      = (const float*)d_in[1];
    const int*   clabel      = (const int*)d_in[2];
    const int*   batch_index = (const int*)d_in[3];
    const int n = in_sizes[0];
    const int nblocks = (n + EPB - 1) / EPB;

    char* ws      = (char*)d_ws;
    u64*  oseg    = (u64*)ws;                                    // 32 KB, memset
    int*  b0_arr  = (int*)(ws + NSEG * sizeof(u64));             // nblocks*4, fully written
    size_t b0_bytes = ((size_t)nblocks * sizeof(int) + 255) & ~(size_t)255;
    u64*  scratch = (u64*)(ws + NSEG * sizeof(u64) + b0_bytes);  // nblocks*2KB, fully written
    float* bl     = (float*)((char*)scratch + (size_t)nblocks * 2 * CLUSTERS * sizeof(u64));
    float* bp     = bl + BATCHES;

    hipMemsetAsync(oseg, 0, NSEG * sizeof(u64), stream);         // ws re-poisoned every call

    seg_accum_kernel<<<nblocks, BLOCK, 0, stream>>>(
        reco, target, clabel, batch_index, scratch, b0_arr, oseg, n);
    batch_reduce_kernel<<<BATCHES, 128, 0, stream>>>(
        scratch, b0_arr, oseg, bl, bp, nblocks);
    final_kernel<<<1, 64, 0, stream>>>(bl, bp, (float*)d_out);
}

// Round 5
// 170.856 us; speedup vs baseline: 2.5237x; 1.1612x over previous
//
#include <hip/hip_runtime.h>

// AutoEncoderLoss: two-level segment-mean MSE over seg = b*128 + c.
// R5: (a) K1 LDS histogram switched u64 -> packed u32 (ds_add_u32, half the
//     LDS atomic bank traffic): enc32 = (1<<21) | round(d^2 * 2^12)
//     (count bits 31:21, max 1024/wave-replica; sum fixed-point, max 512).
//     Widened to u64 (count<<44 | sum) at the non-atomic scratch flush.
// (b) K2: R4's 42us latency-bound serial row-sum (32 blocks x 128 thr, 66-deep
//     loop-carried load chain) replaced by 32 blocks x 1024 threads =
//     8 row-slices x 128 clusters, ~9 independent loads/thread + LDS reduce,
//     fused with the per-batch loss. K3 combines batches.

#define BATCHES 32
#define CLUSTERS 128
#define NSEG (BATCHES * CLUSTERS)
#define BLOCK 256
#define REPS 4                   // one replica per full 64-lane wave
#define EPB 4096                 // elements per block = 256 threads x 4 iters x 4
#define CSHIFT32 21
#define SUM_MASK32 ((1u << CSHIFT32) - 1)
#define SHIFT 44                 // u64 wide format: count<<44 | sum
#define SUM_MASK64 ((1ULL << SHIFT) - 1)
#define SCALE 4096.0f            // 2^12 fixed point
#define INV_SCALE (1.0f / 4096.0f)
#define SLICES 8

typedef unsigned long long u64;
typedef unsigned int u32;

__device__ __forceinline__ u32 enc32(float d) {
    return (1u << CSHIFT32) + __float2uint_rn(d * d * SCALE);
}
__device__ __forceinline__ u64 widen(u32 v) {
    return ((u64)(v >> CSHIFT32) << SHIFT) | (u64)(v & SUM_MASK32);
}

__global__ __launch_bounds__(BLOCK) void seg_accum_kernel(
    const float* __restrict__ reco,
    const float* __restrict__ target,
    const int* __restrict__ clabel,
    const int* __restrict__ batch_index,
    u64* __restrict__ scratch,   // [gridDim.x * 2*CLUSTERS] private row per block
    int* __restrict__ b0_arr,    // [gridDim.x]
    u64* __restrict__ oseg,      // [NSEG] overflow, zeroed, global atomic (rare)
    int n)
{
    __shared__ u32 hist[REPS][2 * CLUSTERS];   // 4 KB
    const int tid  = threadIdx.x;
    const int wave = tid >> 6;

    const long long base = (long long)blockIdx.x * EPB;
    if (base >= n) { if (tid == 0) b0_arr[blockIdx.x] = 0x7fffffff; return; }

    for (int s = tid; s < REPS * 2 * CLUSTERS; s += BLOCK)
        ((u32*)hist)[s] = 0u;
    __syncthreads();

    const long long lim = (base + EPB <= (long long)n) ? base + EPB : (long long)n;
    const int b0 = batch_index[base];
    const int bL = batch_index[lim - 1];
    u32* h = hist[wave];

    if (b0 == bL && base + EPB <= (long long)n) {
        // single-batch full chunk: no per-element batch load
        #pragma unroll
        for (int k = 0; k < EPB / (BLOCK * 4); ++k) {
            const long long idx = base + (long long)(k * BLOCK + tid) * 4;
            const float4 r = *(const float4*)(reco + idx);
            const float4 t = *(const float4*)(target + idx);
            const int4   c = *(const int4*)(clabel + idx);
            atomicAdd(&h[c.x], enc32(r.x - t.x));
            atomicAdd(&h[c.y], enc32(r.y - t.y));
            atomicAdd(&h[c.z], enc32(r.z - t.z));
            atomicAdd(&h[c.w], enc32(r.w - t.w));
        }
    } else {
        // boundary / tail path (~31 of 2048 blocks)
        for (long long idx = base + tid; idx < lim; idx += BLOCK) {
            const float d = reco[idx] - target[idx];
            const int b = batch_index[idx];
            const int c = clabel[idx];
            const int rel = b - b0;
            if (rel < 2) atomicAdd(&h[rel * CLUSTERS + c], enc32(d));
            else         atomicAdd(&oseg[(long long)b * CLUSTERS + c],
                                   ((u64)1 << SHIFT) | (u64)__float2uint_rn(d * d * SCALE));
        }
    }
    __syncthreads();

    // combine replicas -> widen -> non-atomic flush (zeros included; K2 reads
    // both halves unconditionally)
    u64* srow = scratch + (long long)blockIdx.x * (2 * CLUSTERS);
    for (int s = tid; s < 2 * CLUSTERS; s += BLOCK) {
        srow[s] = widen(hist[0][s]) + widen(hist[1][s])
                + widen(hist[2][s]) + widen(hist[3][s]);
    }
    if (tid == 0) b0_arr[blockIdx.x] = b0;
}

__global__ __launch_bounds__(1024) void batch_reduce_kernel(
    const u64* __restrict__ scratch,
    const int* __restrict__ b0_arr,
    const u64* __restrict__ oseg,
    float* __restrict__ bl,      // [BATCHES]
    float* __restrict__ bp,      // [BATCHES]
    int nblocks)
{
    __shared__ u64 part[SLICES][CLUSTERS];     // 8 KB
    __shared__ float ssm[2], snp[2];

    const int b     = blockIdx.x;    // one block per batch
    const int tid   = threadIdx.x;
    const int slice = tid >> 7;      // 0..7
    const int c     = tid & (CLUSTERS - 1);

    // blocks with b0 in {b-1, b} can contribute to batch b (b0_arr sorted)
    int lo = 0, hi = nblocks;
    while (lo < hi) { const int m = (lo + hi) >> 1; if (b0_arr[m] < b - 1) lo = m + 1; else hi = m; }
    int lo2 = lo, hi2 = nblocks;
    while (lo2 < hi2) { const int m = (lo2 + hi2) >> 1; if (b0_arr[m] < b + 1) lo2 = m + 1; else hi2 = m; }

    u64 acc = 0;
    for (int j = lo + slice; j < lo2; j += SLICES) {
        const int off = (b0_arr[j] == b) ? c : (CLUSTERS + c);
        acc += scratch[(long long)j * (2 * CLUSTERS) + off];
    }
    part[slice][c] = acc;
    __syncthreads();

    if (tid < CLUSTERS) {
        u64 tot = oseg[b * CLUSTERS + tid];
        #pragma unroll
        for (int s = 0; s < SLICES; ++s) tot += part[s][tid];

        float sm = 0.0f, np = 0.0f;
        if (tot) {  // nonzero iff count > 0
            const float cnt = (float)(u32)(tot >> SHIFT);
            sm = ((float)(tot & SUM_MASK64) * INV_SCALE) / cnt;
            np = 1.0f;
        }
        #pragma unroll
        for (int off = 32; off; off >>= 1) {
            sm += __shfl_down(sm, off);
            np += __shfl_down(np, off);
        }
        if ((tid & 63) == 0) { ssm[tid >> 6] = sm; snp[tid >> 6] = np; }
    }
    __syncthreads();
    if (tid == 0) {
        const float S = ssm[0] + ssm[1];
        const float P = snp[0] + snp[1];
        bl[b] = (P > 0.0f) ? (S / P) : 0.0f;
        bp[b] = (P > 0.0f) ? 1.0f : 0.0f;
    }
}

__global__ __launch_bounds__(64) void final_kernel(
    const float* __restrict__ bl,
    const float* __restrict__ bp,
    float* __restrict__ out)
{
    const int t = threadIdx.x;
    float s = 0.0f, nb = 0.0f;
    if (t < BATCHES) { s = bl[t]; nb = bp[t]; }
    #pragma unroll
    for (int off = 16; off; off >>= 1) {
        s  += __shfl_down(s, off, 32);
        nb += __shfl_down(nb, off, 32);
    }
    if (t == 0) out[0] = (nb > 0.0f) ? (s / nb) : 0.0f;
}

extern "C" void kernel_launch(void* const* d_in, const int* in_sizes, int n_in,
                              void* d_out, int out_size, void* d_ws, size_t ws_size,
                              hipStream_t stream) {
    const float* reco        = (const float*)d_in[0];
    const float* target      = (const float*)d_in[1];
    const int*   clabel      = (const int*)d_in[2];
    const int*   batch_index = (const int*)d_in[3];
    const int n = in_sizes[0];
    const int nblocks = (n + EPB - 1) / EPB;

    char* ws      = (char*)d_ws;
    u64*  oseg    = (u64*)ws;                                    // 32 KB, memset
    int*  b0_arr  = (int*)(ws + NSEG * sizeof(u64));             // fully written by K1
    size_t b0_bytes = ((size_t)nblocks * sizeof(int) + 255) & ~(size_t)255;
    u64*  scratch = (u64*)(ws + NSEG * sizeof(u64) + b0_bytes);  // fully written by K1
    float* bl     = (float*)((char*)scratch + (size_t)nblocks * 2 * CLUSTERS * sizeof(u64));
    float* bp     = bl + BATCHES;

    hipMemsetAsync(oseg, 0, NSEG * sizeof(u64), stream);         // ws re-poisoned every call

    seg_accum_kernel<<<nblocks, BLOCK, 0, stream>>>(
        reco, target, clabel, batch_index, scratch, b0_arr, oseg, n);
    batch_reduce_kernel<<<BATCHES, SLICES * CLUSTERS, 0, stream>>>(
        scratch, b0_arr, oseg, bl, bp, nblocks);
    final_kernel<<<1, 64, 0, stream>>>(bl, bp, (float*)d_out);
}